// Round 1
// baseline (161.812 us; speedup 1.0000x reference)
//
#include <hip/hip_runtime.h>

// VectorQuantizer: inputs [32,64,64,64] fp32 NCHW, embedding [512,64] fp32.
// out = d_out[0:8388608] quantized NCHW, d_out[8388608] = loss.
// ws layout: [0:512) codebook norms, [512:2560) per-block loss partials.

#define D 64
#define K_EMB 512
#define HW 4096           // 64*64
#define CHW (D * HW)      // per-image stride: 262144
#define OUT_ELEMS 8388608 // 32*64*64*64
#define NBLOCKS 2048      // 131072 rows / 64 rows per block

__global__ void vq_norms(const float* __restrict__ emb, float* __restrict__ norms) {
    int k = blockIdx.x * 64 + threadIdx.x; // <<<8,64>>>
    const float4* e4 = reinterpret_cast<const float4*>(emb + k * D);
    float acc = 0.f;
#pragma unroll
    for (int j = 0; j < D / 4; ++j) {
        float4 v = e4[j];
        acc += v.x * v.x + v.y * v.y + v.z * v.z + v.w * v.w;
    }
    norms[k] = acc;
}

__global__ __launch_bounds__(256) void vq_main(const float* __restrict__ in,
                                               const float* __restrict__ emb,
                                               const float* __restrict__ norms,
                                               float* __restrict__ out,
                                               float* __restrict__ partials) {
    const int lane = threadIdx.x & 63;
    const int w = __builtin_amdgcn_readfirstlane(threadIdx.x >> 6); // wave id 0..3
    const int row0 = blockIdx.x * 64;       // 64 rows per block, same image n
    const int n = row0 >> 12;               // row0 / 4096
    const int hw = (row0 & 4095) + lane;
    const float* xptr = in + n * CHW + hw;  // + c*HW per channel

    // Load this lane's row vector (64 fp32) into registers. Coalesced across
    // lanes per c (contiguous hw). All 4 waves load the same tile (L1 hits).
    float x[D];
#pragma unroll
    for (int c = 0; c < D; ++c) x[c] = xptr[c * HW];

    // Each wave scans its 128-candidate slice. Codebook reads are
    // wave-uniform -> scalar loads. Criterion: ||e||^2 - 2 x.e
    float best = 3.0e38f;
    int bestk = 0;
    const int k0 = w * 128;
    for (int j = 0; j < 128; ++j) {
        const int k = k0 + j;
        const float* __restrict__ e = emb + k * D;
        float a0 = 0.f, a1 = 0.f, a2 = 0.f, a3 = 0.f;
#pragma unroll
        for (int c = 0; c < D; c += 4) {
            a0 = fmaf(x[c + 0], e[c + 0], a0);
            a1 = fmaf(x[c + 1], e[c + 1], a1);
            a2 = fmaf(x[c + 2], e[c + 2], a2);
            a3 = fmaf(x[c + 3], e[c + 3], a3);
        }
        float crit = norms[k] - 2.0f * ((a0 + a1) + (a2 + a3));
        if (crit < best) { best = crit; bestk = k; } // strict <: first-min wins
    }

    __shared__ float bestS[4][64];
    __shared__ int bestkS[4][64];
    bestS[w][lane] = best;
    bestkS[w][lane] = bestk;
    __syncthreads();

    if (w == 0) {
        // Combine across waves; lower wave wins ties (= lower k = np argmin).
        float b = bestS[0][lane];
        int bk = bestkS[0][lane];
#pragma unroll
        for (int q = 1; q < 4; ++q) {
            float bq = bestS[q][lane];
            int bkq = bestkS[q][lane];
            if (bq < b) { b = bq; bk = bkq; }
        }
        const float* __restrict__ eb = emb + bk * D;
        float* obase = out + n * CHW + (row0 & 4095) + lane;
        float lsum = 0.f;
#pragma unroll
        for (int c = 0; c < D; ++c) {
            float e = eb[c];            // divergent gather (L1/L2-resident)
            obase[c * HW] = e;          // coalesced across lanes per c
            float d = e - x[c];
            lsum = fmaf(d, d, lsum);
        }
#pragma unroll
        for (int s = 32; s > 0; s >>= 1) lsum += __shfl_xor(lsum, s, 64);
        if (lane == 0) partials[blockIdx.x] = lsum;
    }
}

__global__ void vq_finalize(const float* __restrict__ partials, float* __restrict__ loss) {
    __shared__ float s[256];
    float a = 0.f;
    for (int i = threadIdx.x; i < NBLOCKS; i += 256) a += partials[i];
    s[threadIdx.x] = a;
    __syncthreads();
    for (int t = 128; t > 0; t >>= 1) {
        if ((int)threadIdx.x < t) s[threadIdx.x] += s[threadIdx.x + t];
        __syncthreads();
    }
    if (threadIdx.x == 0)
        loss[0] = 1.25f * s[0] * (1.0f / (float)OUT_ELEMS);
}

extern "C" void kernel_launch(void* const* d_in, const int* in_sizes, int n_in,
                              void* d_out, int out_size, void* d_ws, size_t ws_size,
                              hipStream_t stream) {
    const float* in = (const float*)d_in[0];
    const float* emb = (const float*)d_in[1];
    float* out = (float*)d_out;
    float* norms = (float*)d_ws;
    float* partials = norms + K_EMB;

    vq_norms<<<8, 64, 0, stream>>>(emb, norms);
    vq_main<<<NBLOCKS, 256, 0, stream>>>(in, emb, norms, out, partials);
    vq_finalize<<<1, 256, 0, stream>>>(partials, out + OUT_ELEMS);
}

// Round 2
// 59.110 us; speedup vs baseline: 2.7375x; 2.7375x over previous
//
#include <hip/hip_runtime.h>

// VectorQuantizer MFMA version.
// inputs: in [32,64,64,64] fp32 NCHW, emb [512,64] fp32.
// out[0:8388608] = quantized NCHW, out[8388608] = loss.
// ws: [0,65536)B emb bf16 row-major; [65536,67584)B normp1 f32; [67584,69632)B partials.

#define D 64
#define K_EMB 512
#define HW 4096
#define CHW (D * HW)
#define OUT_ELEMS 8388608
#define NB_MAIN 512 // 131072 rows / 256 rows per block

typedef __attribute__((ext_vector_type(8))) short short8;
typedef __attribute__((ext_vector_type(4))) float f32x4;

__device__ __forceinline__ unsigned short f2bf(float f) {
    unsigned u = __float_as_uint(f);
    u += 0x7FFFu + ((u >> 16) & 1u); // RNE
    return (unsigned short)(u >> 16);
}
__device__ __forceinline__ float bf2f(unsigned short h) {
    return __uint_as_float(((unsigned)h) << 16);
}
__device__ __forceinline__ unsigned umin32(unsigned a, unsigned b) { return a <= b ? a : b; }

// Prep: codebook fp32 -> bf16 rows + (1 + ||e||^2) per code.
__global__ void vq_prep(const float* __restrict__ emb, unsigned short* __restrict__ ebf,
                        float* __restrict__ np1) {
    int k = blockIdx.x * 256 + threadIdx.x; // <<<2,256>>>
    const float4* e4 = reinterpret_cast<const float4*>(emb + k * D);
    unsigned short h[D];
    float acc = 0.f;
#pragma unroll
    for (int i = 0; i < 16; ++i) {
        float4 v = e4[i];
        acc += v.x * v.x + v.y * v.y + v.z * v.z + v.w * v.w;
        h[4 * i + 0] = f2bf(v.x); h[4 * i + 1] = f2bf(v.y);
        h[4 * i + 2] = f2bf(v.z); h[4 * i + 3] = f2bf(v.w);
    }
    np1[k] = acc + 1.0f;
    uint4* dst = reinterpret_cast<uint4*>(ebf + k * D);
#pragma unroll
    for (int i = 0; i < 8; ++i) {
        uint4 p;
        p.x = (unsigned)h[8 * i + 0] | ((unsigned)h[8 * i + 1] << 16);
        p.y = (unsigned)h[8 * i + 2] | ((unsigned)h[8 * i + 3] << 16);
        p.z = (unsigned)h[8 * i + 4] | ((unsigned)h[8 * i + 5] << 16);
        p.w = (unsigned)h[8 * i + 6] | ((unsigned)h[8 * i + 7] << 16);
        dst[i] = p;
    }
}

__global__ __launch_bounds__(256) void vq_mfma(const float* __restrict__ in,
                                               const unsigned short* __restrict__ ebf,
                                               const float* __restrict__ np1,
                                               const float* __restrict__ emb,
                                               float* __restrict__ out,
                                               float* __restrict__ partials) {
    __shared__ __align__(16) char lds[65536];
    char* ldsX = lds;         // 256 rows x 128B bf16, slot-swizzled
    char* ldsE = lds + 32768; // E half (256 codes x 128B), later bestk + reduce scratch

    const int tid = threadIdx.x;
    const int lane = tid & 63;
    const int w = tid >> 6;
    const int col = lane & 15;
    const int dg = lane >> 4;
    const int bid = blockIdx.x;
    const int n = bid >> 4;
    const int hw0 = (bid & 15) << 8;
    const float* xbase = in + n * CHW + hw0 + tid;

    // ---- stage X tile (transpose NCHW -> [row][d] bf16, XOR swizzle slot^=(row&7)) ----
#pragma unroll
    for (int cg = 0; cg < 8; ++cg) {
        unsigned short h[8];
#pragma unroll
        for (int j = 0; j < 8; ++j) h[j] = f2bf(xbase[(cg * 8 + j) * HW]);
        uint4 p;
        p.x = (unsigned)h[0] | ((unsigned)h[1] << 16);
        p.y = (unsigned)h[2] | ((unsigned)h[3] << 16);
        p.z = (unsigned)h[4] | ((unsigned)h[5] << 16);
        p.w = (unsigned)h[6] | ((unsigned)h[7] << 16);
        *reinterpret_cast<uint4*>(ldsX + tid * 128 + ((cg ^ (tid & 7)) * 16)) = p;
    }
    __syncthreads();

    // ---- A fragments: wave w owns rows w*64..w*64+63 (4 row-tiles of 16) ----
    short8 af[4][2];
#pragma unroll
    for (int rt = 0; rt < 4; ++rt) {
        int row = w * 64 + rt * 16 + col;
#pragma unroll
        for (int kh = 0; kh < 2; ++kh)
            af[rt][kh] = *reinterpret_cast<const short8*>(
                ldsX + row * 128 + (((kh * 4 + dg) ^ (row & 7)) * 16));
    }

    unsigned best[4][4];
#pragma unroll
    for (int rt = 0; rt < 4; ++rt)
#pragma unroll
        for (int i = 0; i < 4; ++i) best[rt][i] = 0xFFFFFFFFu;

    for (int half = 0; half < 2; ++half) {
        // stage E half (pre-converted bf16), linear->swizzled copy, coalesced
        const uint4* esrc = reinterpret_cast<const uint4*>(ebf + half * 256 * D);
#pragma unroll
        for (int i = 0; i < 8; ++i) {
            int q = i * 256 + tid;
            int r = q >> 3, cg = q & 7;
            *reinterpret_cast<uint4*>(ldsE + r * 128 + ((cg ^ (r & 7)) * 16)) = esrc[q];
        }
        __syncthreads();

#pragma unroll
        for (int ctl = 0; ctl < 16; ++ctl) {
            int re = ctl * 16 + col;
            short8 e0 = *reinterpret_cast<const short8*>(
                ldsE + re * 128 + ((dg ^ (re & 7)) * 16));
            short8 e1 = *reinterpret_cast<const short8*>(
                ldsE + re * 128 + (((4 + dg) ^ (re & 7)) * 16));
            int kcode = half * 256 + ctl * 16 + col;
            float np = np1[kcode]; // 2KB, L1-hot
#pragma unroll
            for (int rt = 0; rt < 4; ++rt) {
                f32x4 acc = {0.f, 0.f, 0.f, 0.f};
                acc = __builtin_amdgcn_mfma_f32_16x16x32_bf16(af[rt][0], e0, acc, 0, 0, 0);
                acc = __builtin_amdgcn_mfma_f32_16x16x32_bf16(af[rt][1], e1, acc, 0, 0, 0);
#pragma unroll
                for (int i = 0; i < 4; ++i) {
                    // crit = 1 + ||e||^2 - 2 x.e  (always > 0 -> uint order = float order)
                    float crit = fmaf(-2.f, acc[i], np);
                    unsigned key = (__float_as_uint(crit) & 0xFFFFFE00u) | (unsigned)kcode;
                    best[rt][i] = umin32(best[rt][i], key);
                }
            }
        }
        __syncthreads(); // before E restage / bestk overwrite
    }

    // ---- per-row argmin: reduce over the 16 code-columns (lanes sharing dg) ----
    int* bestk_lds = reinterpret_cast<int*>(ldsE);
#pragma unroll
    for (int rt = 0; rt < 4; ++rt)
#pragma unroll
        for (int i = 0; i < 4; ++i) {
            unsigned k = best[rt][i];
#pragma unroll
            for (int s = 1; s < 16; s <<= 1)
                k = umin32(k, (unsigned)__shfl_xor((int)k, s, 64));
            if (col == 0) bestk_lds[w * 64 + rt * 16 + dg * 4 + i] = (int)(k & 511u);
        }
    __syncthreads();

    // ---- epilogue: thread owns 4 rows x 16 channels; float4 stores along hw ----
    const int q = tid >> 6;
    const int r0 = (tid & 63) * 4;
    int kk[4];
#pragma unroll
    for (int j = 0; j < 4; ++j) kk[j] = bestk_lds[r0 + j];
    float4 ea[4][4]; // [row][c-subquad] = e[kk[row]][q*16 + m*4 .. +3]
#pragma unroll
    for (int j = 0; j < 4; ++j) {
        const float4* ep = reinterpret_cast<const float4*>(emb + kk[j] * D + q * 16);
#pragma unroll
        for (int m = 0; m < 4; ++m) ea[j][m] = ep[m];
    }
    float lsum = 0.f;
#pragma unroll
    for (int j = 0; j < 4; ++j) {
        int r = r0 + j;
        short8 xa = *reinterpret_cast<const short8*>(
            ldsX + r * 128 + (((q * 2) ^ (r & 7)) * 16));
        short8 xb = *reinterpret_cast<const short8*>(
            ldsX + r * 128 + (((q * 2 + 1) ^ (r & 7)) * 16));
        const float* ej = reinterpret_cast<const float*>(&ea[j][0]);
#pragma unroll
        for (int t2 = 0; t2 < 8; ++t2) {
            float d = ej[t2] - bf2f((unsigned short)xa[t2]);
            lsum = fmaf(d, d, lsum);
        }
#pragma unroll
        for (int t2 = 0; t2 < 8; ++t2) {
            float d = ej[8 + t2] - bf2f((unsigned short)xb[t2]);
            lsum = fmaf(d, d, lsum);
        }
    }
    float* obase = out + n * CHW + hw0 + r0;
#pragma unroll
    for (int m = 0; m < 4; ++m) {
#pragma unroll
        for (int cc = 0; cc < 4; ++cc) {
            int c = q * 16 + m * 4 + cc;
            const float* e0 = reinterpret_cast<const float*>(&ea[0][m]);
            const float* e1 = reinterpret_cast<const float*>(&ea[1][m]);
            const float* e2 = reinterpret_cast<const float*>(&ea[2][m]);
            const float* e3 = reinterpret_cast<const float*>(&ea[3][m]);
            float4 st;
            st.x = e0[cc]; st.y = e1[cc]; st.z = e2[cc]; st.w = e3[cc];
            *reinterpret_cast<float4*>(obase + c * HW) = st;
        }
    }
    // loss partial
#pragma unroll
    for (int s = 1; s < 64; s <<= 1) lsum += __shfl_xor(lsum, s, 64);
    float* red = reinterpret_cast<float*>(ldsE + 2048);
    if (lane == 0) red[w] = lsum;
    __syncthreads();
    if (tid == 0) partials[bid] = red[0] + red[1] + red[2] + red[3];
}

__global__ void vq_finalize(const float* __restrict__ partials, float* __restrict__ loss) {
    __shared__ float s[256];
    float a = 0.f;
    for (int i = threadIdx.x; i < NB_MAIN; i += 256) a += partials[i];
    s[threadIdx.x] = a;
    __syncthreads();
    for (int t = 128; t > 0; t >>= 1) {
        if ((int)threadIdx.x < t) s[threadIdx.x] += s[threadIdx.x + t];
        __syncthreads();
    }
    if (threadIdx.x == 0) loss[0] = 1.25f * s[0] * (1.0f / (float)OUT_ELEMS);
}

extern "C" void kernel_launch(void* const* d_in, const int* in_sizes, int n_in,
                              void* d_out, int out_size, void* d_ws, size_t ws_size,
                              hipStream_t stream) {
    const float* in = (const float*)d_in[0];
    const float* emb = (const float*)d_in[1];
    float* out = (float*)d_out;
    unsigned short* ebf = (unsigned short*)d_ws;
    float* np1 = (float*)((char*)d_ws + 65536);
    float* partials = (float*)((char*)d_ws + 67584);

    vq_prep<<<2, 256, 0, stream>>>(emb, ebf, np1);
    vq_mfma<<<NB_MAIN, 256, 0, stream>>>(in, ebf, np1, emb, out, partials);
    vq_finalize<<<1, 256, 0, stream>>>(partials, out + OUT_ELEMS);
}